// Round 3
// baseline (265.478 us; speedup 1.0000x reference)
//
#include <hip/hip_runtime.h>
#include <hip/hip_bf16.h>

#define DEV static __device__ __forceinline__

typedef __attribute__((ext_vector_type(8))) short bf16x8;
typedef __attribute__((ext_vector_type(4))) float f32x4;
typedef __attribute__((ext_vector_type(4))) unsigned int u32x4;
typedef __attribute__((ext_vector_type(2))) unsigned int u32x2;
typedef unsigned int u32;
typedef unsigned short u16;

static constexpr int S = 4096, E = 1024;

DEV u16 f2bf(float f) {
  union { float f; u32 u; } v; v.f = f;
  return (u16)((v.u + 0x7fffu + ((v.u >> 16) & 1u)) >> 16);
}

#define MFMA16(a, b, c) __builtin_amdgcn_mfma_f32_16x16x32_bf16(a, b, c, 0, 0, 0)

// ---------------- k0: W [1024][64] f32 -> Wt [192 n][1024 k] bf16 (Q scaled) ---
__global__ __launch_bounds__(256) void wtrans_kernel(const float* __restrict__ Wq,
    const float* __restrict__ Wk, const float* __restrict__ Wv, u16* __restrict__ Wt) {
  __shared__ u16 ls[64][72];
  const int t = threadIdx.x;
  const int mat = blockIdx.x >> 4, kt = blockIdx.x & 15;
  const float* W = (mat == 0) ? Wq : ((mat == 1) ? Wk : Wv);
  const float scale = (mat == 0) ? 0.125f : 1.0f;  // fold 1/sqrt(64) into Wq
  const int kr = t >> 2, n0 = (t & 3) * 16;
  const float* src = W + (kt * 64 + kr) * 64 + n0;
  #pragma unroll
  for (int i = 0; i < 16; ++i) ls[n0 + i][kr] = f2bf(src[i] * scale);
  __syncthreads();
  const int n = t >> 2, kc = (t & 3) * 16;
  const unsigned char* lp = (const unsigned char*)&ls[n][0] + kc * 2;
  u32x4 a = *(const u32x4*)lp;
  u32x4 b = *(const u32x4*)(lp + 16);
  u16* dst = Wt + mat * 65536 + n * 1024 + kt * 64 + kc;
  *(u32x4*)dst = a;
  *(u32x4*)(dst + 8) = b;
}

// ---------------- k1: QKV projection, LDS-free streaming ----------------
// grid 1024 x 128 threads (2 independent waves). Wave: 16 rows x 96 cols.
__global__ __launch_bounds__(128) void proj_kernel(const float* __restrict__ x,
    const u16* __restrict__ Wt, u16* __restrict__ Qo, u16* __restrict__ Ko,
    u16* __restrict__ Vo) {
  const int t = threadIdx.x, l = t & 63, w = t >> 6;
  const int g = l >> 4, c = l & 15;
  const int m0 = blockIdx.x * 16;
  const float* xp = x + (size_t)(m0 + c) * E + 8 * g;
  const u16* wp = Wt + (size_t)(96 * w + c) * E + 8 * g;   // + nf*16*1024, + kt*32

  f32x4 acc[6];
  #pragma unroll
  for (int i = 0; i < 6; ++i) acc[i] = f32x4{0.f, 0.f, 0.f, 0.f};

  f32x4 xb[4][2];          // x prefetch depth 4 (HBM latency)
  bf16x8 wb[2][6];         // W prefetch depth 2 (L2 latency)
  #pragma unroll
  for (int p = 0; p < 4; ++p) {
    xb[p][0] = *(const f32x4*)(xp + p * 32);
    xb[p][1] = *(const f32x4*)(xp + p * 32 + 4);
  }
  #pragma unroll
  for (int p = 0; p < 2; ++p)
    #pragma unroll
    for (int nf = 0; nf < 6; ++nf)
      wb[p][nf] = *(const bf16x8*)(wp + nf * 16384 + p * 32);

  #pragma unroll
  for (int kt = 0; kt < 32; ++kt) {
    const int xs = kt & 3, wsl = kt & 1;
    // convert current x chunk to bf16 A-frag (f2bf pairs; compiler packs)
    u32x4 aw;
    aw[0] = (u32)f2bf(xb[xs][0][0]) | ((u32)f2bf(xb[xs][0][1]) << 16);
    aw[1] = (u32)f2bf(xb[xs][0][2]) | ((u32)f2bf(xb[xs][0][3]) << 16);
    aw[2] = (u32)f2bf(xb[xs][1][0]) | ((u32)f2bf(xb[xs][1][1]) << 16);
    aw[3] = (u32)f2bf(xb[xs][1][2]) | ((u32)f2bf(xb[xs][1][3]) << 16);
    bf16x8 af = __builtin_bit_cast(bf16x8, aw);
    #pragma unroll
    for (int nf = 0; nf < 6; ++nf)
      acc[nf] = MFMA16(af, wb[wsl][nf], acc[nf]);
    // refill consumed slots
    if (kt < 28) {
      xb[xs][0] = *(const f32x4*)(xp + (kt + 4) * 32);
      xb[xs][1] = *(const f32x4*)(xp + (kt + 4) * 32 + 4);
    }
    if (kt < 30) {
      #pragma unroll
      for (int nf = 0; nf < 6; ++nf)
        wb[wsl][nf] = *(const bf16x8*)(wp + nf * 16384 + (kt + 2) * 32);
    }
  }

  // epilogue: D row = 4g+r, col c; n = 96w + 16nf + c
  const int b = m0 >> 12, sloc = m0 & 4095;
  #pragma unroll
  for (int nf = 0; nf < 6; ++nf) {
    const int n = 96 * w + 16 * nf + c;
    if (n < 64) {
      #pragma unroll
      for (int r = 0; r < 4; ++r)
        Qo[(size_t)(m0 + 4 * g + r) * 64 + n] = f2bf(acc[nf][r]);
    } else if (n < 128) {
      #pragma unroll
      for (int r = 0; r < 4; ++r)
        Ko[(size_t)(m0 + 4 * g + r) * 64 + (n - 64)] = f2bf(acc[nf][r]);
    } else {
      const int d = n - 128;
      u32 w0 = (u32)f2bf(acc[nf][0]) | ((u32)f2bf(acc[nf][1]) << 16);
      u32 w1 = (u32)f2bf(acc[nf][2]) | ((u32)f2bf(acc[nf][3]) << 16);
      *(u32x2*)(Vo + ((size_t)b * 64 + d) * S + sloc + 4 * g) = u32x2{w0, w1};
    }
  }
}

// ---------------- k2: flash attention, in-block KV-split x4 ----------------
// grid (256,4) x 256 threads. Block: 16 q-rows; wave w: kv in [w*1024,(w+1)*1024).
// No barriers in main loop; one __syncthreads before the in-LDS combine.
// 16x16x32 MFMA, round-1-verified fragment paths. Q pre-scaled (wtrans).
__global__ __launch_bounds__(256, 4) void attn_kernel(const u16* __restrict__ Q,
    const u16* __restrict__ K, const u16* __restrict__ Vt, float* __restrict__ out) {
  __shared__ unsigned char Pb[4][2048];   // per-wave P[q 16][kv 64] bf16, swizzled
  __shared__ float accb[4][16][64];       // per-wave unnormalized O
  __shared__ float2 mlb[4][16];           // per-wave (m, l) per q-row
  const int t = threadIdx.x, l = t & 63, w = t >> 6;
  const int g = l >> 4, c = l & 15;
  // batch-major swizzle: XCD k (round-robin by linear id) serves batch k&3 only
  const int flat = blockIdx.x + (blockIdx.y << 8);
  const int b = flat & 3, q0 = (flat >> 2) * 16;
  const int kv0 = w * 1024;
  const float L2E = 1.4426950408889634f;

  // Q B-frags: B[k=d][col=q=c], k = 8g+j (+32 ks)
  const u16* Qp = Q + ((size_t)b * S + q0 + c) * 64 + 8 * g;
  bf16x8 qf[2];
  qf[0] = *(const bf16x8*)(Qp);
  qf[1] = *(const bf16x8*)(Qp + 32);

  const u16* Kp = K + ((size_t)b * S + kv0) * 64;
  const u16* Vp = Vt + (size_t)b * 64 * S + kv0;

  f32x4 acc[4];
  #pragma unroll
  for (int i = 0; i < 4; ++i) acc[i] = f32x4{0.f, 0.f, 0.f, 0.f};
  float mrun = -1e30f, lrun = 0.f;

  for (int kt = 0; kt < 16; ++kt) {
    // K A-frags direct from global: A[row=kv=16mf+c][k=d=32ks+8g+j]
    bf16x8 kf[4][2];
    #pragma unroll
    for (int mf = 0; mf < 4; ++mf)
      #pragma unroll
      for (int ks = 0; ks < 2; ++ks)
        kf[mf][ks] = *(const bf16x8*)(Kp + (size_t)(kt * 64 + 16 * mf + c) * 64 + 32 * ks + 8 * g);
    // S^T = K * Q^T : lane owns q=c, kv rows 16mf + 4g + r
    f32x4 sf[4];
    #pragma unroll
    for (int i = 0; i < 4; ++i) sf[i] = f32x4{0.f, 0.f, 0.f, 0.f};
    #pragma unroll
    for (int ks = 0; ks < 2; ++ks)
      #pragma unroll
      for (int mf = 0; mf < 4; ++mf)
        sf[mf] = MFMA16(kf[mf][ks], qf[ks], sf[mf]);
    // online softmax for q=c: 16 local vals, reduce across g via xor 16,32
    float tmax = -1e30f;
    #pragma unroll
    for (int mf = 0; mf < 4; ++mf)
      #pragma unroll
      for (int r = 0; r < 4; ++r) tmax = fmaxf(tmax, sf[mf][r]);
    tmax = fmaxf(tmax, __shfl_xor(tmax, 16));
    tmax = fmaxf(tmax, __shfl_xor(tmax, 32));
    const float mnew = fmaxf(mrun, tmax);
    const float alpha = exp2f((mrun - mnew) * L2E);
    float psum = 0.f;
    u32 pkv[4][2];
    #pragma unroll
    for (int mf = 0; mf < 4; ++mf) {
      float p0 = exp2f((sf[mf][0] - mnew) * L2E);
      float p1 = exp2f((sf[mf][1] - mnew) * L2E);
      float p2 = exp2f((sf[mf][2] - mnew) * L2E);
      float p3 = exp2f((sf[mf][3] - mnew) * L2E);
      psum += (p0 + p1) + (p2 + p3);
      pkv[mf][0] = (u32)f2bf(p0) | ((u32)f2bf(p1) << 16);
      pkv[mf][1] = (u32)f2bf(p2) | ((u32)f2bf(p3) << 16);
    }
    psum += __shfl_xor(psum, 16);
    psum += __shfl_xor(psum, 32);
    lrun = lrun * alpha + psum;
    mrun = mnew;
    // P -> per-wave LDS (row q=c, swizzled); same-wave RAW, no barrier needed
    unsigned char* pb = Pb[w] + c * 128;
    #pragma unroll
    for (int mf = 0; mf < 4; ++mf)
      *(u32x2*)(pb + ((32 * mf + 8 * g) ^ ((c & 7) << 4))) = u32x2{pkv[mf][0], pkv[mf][1]};
    // rescale acc: acc row q = 4g+r -> alpha from lane c=4g+r (group g)
    float ar[4];
    #pragma unroll
    for (int r = 0; r < 4; ++r) ar[r] = __shfl(alpha, 20 * g + r);
    #pragma unroll
    for (int nf = 0; nf < 4; ++nf)
      #pragma unroll
      for (int r = 0; r < 4; ++r) acc[nf][r] *= ar[r];
    // PV: A = P[q=c][kv=32ks+8g+j], B = V[kv][d=c+16nf] from Vt direct
    #pragma unroll
    for (int ks = 0; ks < 2; ++ks) {
      bf16x8 pfr = *(const bf16x8*)(pb + ((16 * g + 64 * ks) ^ ((c & 7) << 4)));
      #pragma unroll
      for (int nf = 0; nf < 4; ++nf) {
        bf16x8 vf = *(const bf16x8*)(Vp + (size_t)(16 * nf + c) * S + kt * 64 + 32 * ks + 8 * g);
        acc[nf] = MFMA16(pfr, vf, acc[nf]);
      }
    }
  }

  // publish per-wave partials
  #pragma unroll
  for (int nf = 0; nf < 4; ++nf)
    #pragma unroll
    for (int r = 0; r < 4; ++r)
      accb[w][4 * g + r][c + 16 * nf] = acc[nf][r];
  if (g == 0) mlb[w][c] = make_float2(mrun, lrun);
  __syncthreads();

  // combine 4 splits: thread t -> q = t>>4, d0 = (t&15)*4. den >= 1 always.
  const int q = t >> 4, d0 = (t & 15) * 4;
  const float2 ml0 = mlb[0][q], ml1 = mlb[1][q], ml2 = mlb[2][q], ml3 = mlb[3][q];
  const float m = fmaxf(fmaxf(ml0.x, ml1.x), fmaxf(ml2.x, ml3.x));
  const float e0 = exp2f((ml0.x - m) * L2E);
  const float e1 = exp2f((ml1.x - m) * L2E);
  const float e2 = exp2f((ml2.x - m) * L2E);
  const float e3 = exp2f((ml3.x - m) * L2E);
  const float den = e0 * ml0.y + e1 * ml1.y + e2 * ml2.y + e3 * ml3.y;
  const f32x4 n0 = *(const f32x4*)&accb[0][q][d0];
  const f32x4 n1 = *(const f32x4*)&accb[1][q][d0];
  const f32x4 n2 = *(const f32x4*)&accb[2][q][d0];
  const f32x4 n3 = *(const f32x4*)&accb[3][q][d0];
  const float inv = 1.f / den;
  f32x4 res;
  #pragma unroll
  for (int j = 0; j < 4; ++j)
    res[j] = (e0 * n0[j] + e1 * n1[j] + e2 * n2[j] + e3 * n3[j]) * inv;
  *(f32x4*)(out + ((size_t)b * S + q0 + q) * 64 + d0) = res;
}

extern "C" void kernel_launch(void* const* d_in, const int* in_sizes, int n_in,
                              void* d_out, int out_size, void* d_ws, size_t ws_size,
                              hipStream_t stream) {
  const float* x  = (const float*)d_in[0];
  const float* Wq = (const float*)d_in[1];
  const float* Wk = (const float*)d_in[2];
  const float* Wv = (const float*)d_in[3];
  float* out = (float*)d_out;
  char* ws = (char*)d_ws;
  // ws layout: Wt 384KB | Q 2MB | K 2MB | Vt 2MB  (6.375 MB, round-1-proven size)
  u16* Wt = (u16*)(ws);
  u16* Q  = (u16*)(ws + 0x60000);
  u16* K  = (u16*)(ws + 0x260000);
  u16* Vt = (u16*)(ws + 0x460000);

  hipLaunchKernelGGL(wtrans_kernel, dim3(48), dim3(256), 0, stream, Wq, Wk, Wv, Wt);
  hipLaunchKernelGGL(proj_kernel, dim3(1024), dim3(128), 0, stream, x, Wt, Q, K, Vt);
  hipLaunchKernelGGL(attn_kernel, dim3(256, 4), dim3(256), 0, stream, Q, K, Vt, out);
}

// Round 5
// 144.353 us; speedup vs baseline: 1.8391x; 1.8391x over previous
//
#include <hip/hip_runtime.h>
#include <hip/hip_bf16.h>

#define DEV static __device__ __forceinline__

typedef __attribute__((ext_vector_type(8))) short bf16x8;
typedef __attribute__((ext_vector_type(16))) float f32x16;
typedef __attribute__((ext_vector_type(4))) float f32x4;
typedef __attribute__((ext_vector_type(4))) unsigned int u32x4;
typedef unsigned int u32;
typedef unsigned short u16;

static constexpr int S = 4096, E = 1024;

DEV u16 f2bf(float f) {
  union { float f; u32 u; } v; v.f = f;
  return (u16)((v.u + 0x7fffu + ((v.u >> 16) & 1u)) >> 16);
}
DEV u32 pk2(float lo, float hi) {
  return (u32)__bfloat16_as_ushort(__float2bfloat16(lo)) |
         ((u32)__bfloat16_as_ushort(__float2bfloat16(hi)) << 16);
}
DEV float exp2a(float x) {
  float r;
  asm("v_exp_f32 %0, %1" : "=v"(r) : "v"(x));
  return r;
}
DEV u32 sx32(u32 v) { return (u32)__shfl_xor((int)v, 32); }

DEV void gload16(const void* g, void* l) {
  __builtin_amdgcn_global_load_lds(
      (const __attribute__((address_space(1))) u32*)g,
      (__attribute__((address_space(3))) u32*)l, 16, 0, 0);
}

#define MFMA16(a, b, c) __builtin_amdgcn_mfma_f32_16x16x32_bf16(a, b, c, 0, 0, 0)
#define MFMA32(a, b, c) __builtin_amdgcn_mfma_f32_32x32x16_bf16(a, b, c, 0, 0, 0)

// ---------------- k0: W [1024][64] f32 -> Wt [192 n][1024 k] bf16 ----------------
// Wq gets 0.125 * log2(e) folded in (fixed-base exp2 softmax downstream).
__global__ __launch_bounds__(256) void wtrans_kernel(const float* __restrict__ Wq,
    const float* __restrict__ Wk, const float* __restrict__ Wv, u16* __restrict__ Wt) {
  __shared__ u16 ls[64][72];
  const int t = threadIdx.x;
  const int mat = blockIdx.x >> 4, kt = blockIdx.x & 15;
  const float* W = (mat == 0) ? Wq : ((mat == 1) ? Wk : Wv);
  const float scale = (mat == 0) ? 0.18033688011112042f : 1.0f;  // 0.125*log2e
  const int kr = t >> 2, n0 = (t & 3) * 16;
  const float* src = W + (kt * 64 + kr) * 64 + n0;
  #pragma unroll
  for (int i = 0; i < 16; ++i) ls[n0 + i][kr] = f2bf(src[i] * scale);
  __syncthreads();
  const int n = t >> 2, kc = (t & 3) * 16;
  const unsigned char* lp = (const unsigned char*)&ls[n][0] + kc * 2;
  u32x4 a = *(const u32x4*)lp;
  u32x4 b = *(const u32x4*)(lp + 16);
  u16* dst = Wt + mat * 65536 + n * 1024 + kt * 64 + kc;
  *(u32x4*)dst = a;
  *(u32x4*)(dst + 8) = b;
}

// ---------------- k1: QKV projection, LDS-tiled, coalesced epilogue ----------------
// 512 blocks x 256 thr (4 warps). Block: 32 m-rows x 192 n. K=1024 in 16 chunks of 64.
// Outputs: Q row-major bf16; K,V in MFMA-fragment-major 32-tile layout for attn.
__global__ __launch_bounds__(256) void proj_kernel(const float* __restrict__ x,
    const u16* __restrict__ Wt, u16* __restrict__ Qo, u16* __restrict__ Kf,
    u16* __restrict__ Vf) {
  __shared__ unsigned char pool[57344];  // Xs[2]@0..8K, Ws[2]@8K..56K; Cb aliases @8K
  const int t = threadIdx.x, l = t & 63, w = t >> 6;
  const int g = l >> 4, c = l & 15;
  const int s0 = blockIdx.x * 32;
  const int b = s0 >> 12, tile = (s0 & 4095) >> 5;

  auto Xs = [&](int buf) { return pool + buf * 4096; };
  auto Ws = [&](int buf) { return pool + 8192 + buf * 24576; };

  const int xrow = t >> 3, xcol = (t & 7) * 8;
  const float* xp = x + (size_t)(s0 + xrow) * E + xcol;

  f32x4 acc[2][3];
  #pragma unroll
  for (int i = 0; i < 2; ++i)
    #pragma unroll
    for (int j = 0; j < 3; ++j) acc[i][j] = f32x4{0.f, 0.f, 0.f, 0.f};

  f32x4 xa, xb_;
  auto xload = [&](int kt) {
    const f32x4* p = (const f32x4*)(xp + kt * 64);
    xa = p[0]; xb_ = p[1];
  };
  auto xstore = [&](int buf) {
    u32x4 pk;
    pk[0] = pk2(xa[0], xa[1]);  pk[1] = pk2(xa[2], xa[3]);
    pk[2] = pk2(xb_[0], xb_[1]); pk[3] = pk2(xb_[2], xb_[3]);
    *(u32x4*)(Xs(buf) + xrow * 128 + ((xcol * 2) ^ ((xrow & 7) << 4))) = pk;
  };
  auto wstage = [&](int buf, int kt) {
    #pragma unroll
    for (int i = 0; i < 6; ++i) {
      const int row = (w * 6 + i) * 8 + (l >> 3);
      const unsigned char* src = (const unsigned char*)Wt + (size_t)row * 2048 +
          kt * 128 + (((l & 7) * 16) ^ ((row & 7) << 4));
      gload16(src, Ws(buf) + (w * 6 + i) * 1024);
    }
  };
  auto compute = [&](int buf) {
    #pragma unroll
    for (int ch = 0; ch < 2; ++ch) {
      bf16x8 af[2];
      #pragma unroll
      for (int mf = 0; mf < 2; ++mf) {
        const int row = 16 * mf + c;
        // slice ch covers k-elements [32ch, 32ch+32) -> byte offset 64*ch
        af[mf] = *(const bf16x8*)(Xs(buf) + row * 128 + ((64 * ch + 16 * g) ^ ((row & 7) << 4)));
      }
      #pragma unroll
      for (int nf = 0; nf < 3; ++nf) {
        const int row = 48 * w + 16 * nf + c;
        bf16x8 bf = *(const bf16x8*)(Ws(buf) + row * 128 + ((64 * ch + 16 * g) ^ ((row & 7) << 4)));
        #pragma unroll
        for (int mf = 0; mf < 2; ++mf) acc[mf][nf] = MFMA16(af[mf], bf, acc[mf][nf]);
      }
    }
  };

  xload(0); wstage(0, 0); xstore(0);
  __syncthreads();
  for (int kt = 0; kt < 16; ++kt) {
    const int cur = kt & 1;
    if (kt < 15) { xload(kt + 1); wstage(cur ^ 1, kt + 1); }
    compute(cur);
    if (kt < 15) xstore(cur ^ 1);
    __syncthreads();
  }

  // epilogue: acc -> Cb[32 s][200 pad] bf16, then coalesced writers.
  u16* Cb = (u16*)(pool + 8192);
  #pragma unroll
  for (int mf = 0; mf < 2; ++mf)
    #pragma unroll
    for (int nf = 0; nf < 3; ++nf)
      #pragma unroll
      for (int r = 0; r < 4; ++r)
        Cb[(16 * mf + 4 * g + r) * 200 + 48 * w + 16 * nf + c] =
            __bfloat16_as_ushort(__float2bfloat16(acc[mf][nf][r]));
  __syncthreads();
  {  // Q row-major
    const int s = t >> 3, p = t & 7;
    u32x4 v = *(const u32x4*)(Cb + s * 200 + p * 8);
    *(u32x4*)(Qo + (size_t)(s0 + s) * 64 + p * 8) = v;
  }
  {  // K fragment-major: content K[s0+(l&31)][d=16*c64+8*h+j]
    const int c64 = t >> 6, h = l >> 5;
    u32x4 v = *(const u32x4*)(Cb + (l & 31) * 200 + 64 + 16 * c64 + 8 * h);
    *(u32x4*)(Kf + (size_t)b * 262144 + tile * 2048 + c64 * 512 + l * 8) = v;
  }
  {  // V fragment-major: content V[s0+8h+16cc+j][d=32*dh+(l&31)], idx=2*dh+cc
    const int idx = t >> 6, dh = idx >> 1, cc = idx & 1, h = l >> 5;
    u32x4 v;
    #pragma unroll
    for (int pr = 0; pr < 4; ++pr) {
      u32 e0 = Cb[(8 * h + 16 * cc + 2 * pr) * 200 + 128 + 32 * dh + (l & 31)];
      u32 e1 = Cb[(8 * h + 16 * cc + 2 * pr + 1) * 200 + 128 + 32 * dh + (l & 31)];
      v[pr] = e0 | (e1 << 16);
    }
    *(u32x4*)(Vf + (size_t)b * 262144 + tile * 2048 + idx * 512 + l * 8) = v;
  }
}

// ---------------- k2: attention, fixed-base softmax, zero-LDS main loop ----------------
// 512 blocks x 256 thr. Block: 32 q-rows; warp w scans kv [w*1024, w*1024+1024).
// All K/V loads coalesced (fragment-major). Combine 4 partial (num,den) in LDS.
__global__ __launch_bounds__(256) void attn_kernel(const u16* __restrict__ Q,
    const u16* __restrict__ Kf, const u16* __restrict__ Vf, float* __restrict__ out) {
  __shared__ float accb[4][32][68];
  __shared__ float denb[4][32];
  const int t = threadIdx.x, l = t & 63, w = t >> 6;
  const int h = l >> 5, q = l & 31;
  const int bid = blockIdx.x;
  const int swz = (bid & 7) * 64 + (bid >> 3);  // XCD chunk swizzle (512%8==0)
  const int b = swz >> 7, q0 = (swz & 127) * 32;

  // Q B-frags: lane holds Q[q0+q][d=16c+8h+j]
  const u16* Qp = Q + (size_t)(b * S + q0 + q) * 64;
  bf16x8 qf[4];
  #pragma unroll
  for (int cch = 0; cch < 4; ++cch) qf[cch] = *(const bf16x8*)(Qp + 16 * cch + 8 * h);

  const unsigned char* KfC = (const unsigned char*)(Kf + (size_t)b * 262144);
  const unsigned char* VfC = (const unsigned char*)(Vf + (size_t)b * 262144);
  const int tbase = w * 32;

  f32x16 acc0 = {}, acc1 = {};
  float den = 0.f;

  struct KV { bf16x8 k[4]; bf16x8 v[4]; };
  KV A, B;
  auto load = [&](KV& dst, int tt) {
    const unsigned char* kp = KfC + (size_t)(tbase + tt) * 4096 + l * 16;
    #pragma unroll
    for (int cch = 0; cch < 4; ++cch) dst.k[cch] = *(const bf16x8*)(kp + cch * 1024);
    const unsigned char* vp = VfC + (size_t)(tbase + tt) * 4096 + l * 16;
    #pragma unroll
    for (int i = 0; i < 4; ++i) dst.v[i] = *(const bf16x8*)(vp + i * 1024);
  };
  auto step = [&](KV& cur, KV& nxt, int tt) {
    if (tt < 31) load(nxt, tt + 1);
    // S^T[kv][q] = K_tile x Q^T (lane: col q, kv rows (reg&3)+8*(reg>>2)+4h)
    f32x16 st = {};
    #pragma unroll
    for (int cch = 0; cch < 4; ++cch) st = MFMA32(cur.k[cch], qf[cch], st);
    float p[16];
    #pragma unroll
    for (int i = 0; i < 16; ++i) p[i] = exp2a(st[i]);
    float s01 = (p[0] + p[1]) + (p[2] + p[3]);
    float s23 = (p[4] + p[5]) + (p[6] + p[7]);
    float s45 = (p[8] + p[9]) + (p[10] + p[11]);
    float s67 = (p[12] + p[13]) + (p[14] + p[15]);
    den += (s01 + s23) + (s45 + s67);
    // assemble P^T B-frags: lane needs kv = 8h+j (+16cc); half from partner l^32
    u32 c01 = pk2(p[0], p[1]), c23 = pk2(p[2], p[3]);
    u32 c45 = pk2(p[4], p[5]), c67 = pk2(p[6], p[7]);
    u32 d01 = pk2(p[8], p[9]), d23 = pk2(p[10], p[11]);
    u32 d45 = pk2(p[12], p[13]), d67 = pk2(p[14], p[15]);
    u32 r0 = sx32(h ? c01 : c45), r1 = sx32(h ? c23 : c67);
    u32 r2 = sx32(h ? d01 : d45), r3 = sx32(h ? d23 : d67);
    u32x4 B0 = {h ? r0 : c01, h ? r1 : c23, h ? c45 : r0, h ? c67 : r1};
    u32x4 B1 = {h ? r2 : d01, h ? r3 : d23, h ? d45 : r2, h ? d67 : r3};
    bf16x8 pb0 = __builtin_bit_cast(bf16x8, B0);
    bf16x8 pb1 = __builtin_bit_cast(bf16x8, B1);
    // O^T += V^T x P^T : acc0 rows d 0..31, acc1 rows d 32..63
    acc0 = MFMA32(cur.v[0], pb0, acc0);
    acc1 = MFMA32(cur.v[2], pb0, acc1);
    acc0 = MFMA32(cur.v[1], pb1, acc0);
    acc1 = MFMA32(cur.v[3], pb1, acc1);
  };

  load(A, 0);
  for (int tt = 0; tt < 32; tt += 2) { step(A, B, tt); step(B, A, tt + 1); }

  den += __shfl_xor(den, 32);
  #pragma unroll
  for (int reg = 0; reg < 16; ++reg) {
    const int dr = (reg & 3) + 8 * (reg >> 2) + 4 * h;
    accb[w][q][dr] = acc0[reg];
    accb[w][q][dr + 32] = acc1[reg];
  }
  if (h == 0) denb[w][q] = den;
  __syncthreads();

  // combine: thread -> q-row t>>3, d0 = (t&7)*8
  const int cq = t >> 3, d0 = (t & 7) * 8;
  const float ds = denb[0][cq] + denb[1][cq] + denb[2][cq] + denb[3][cq];
  f32x4 n0 = {}, n1 = {};
  #pragma unroll
  for (int w2 = 0; w2 < 4; ++w2) {
    n0 += *(const f32x4*)&accb[w2][cq][d0];
    n1 += *(const f32x4*)&accb[w2][cq][d0 + 4];
  }
  const float inv = 1.f / ds;
  float* op = out + (size_t)(b * S + q0 + cq) * 64 + d0;
  f32x4 o0, o1;
  #pragma unroll
  for (int j = 0; j < 4; ++j) { o0[j] = n0[j] * inv; o1[j] = n1[j] * inv; }
  *(f32x4*)op = o0;
  *(f32x4*)(op + 4) = o1;
}

extern "C" void kernel_launch(void* const* d_in, const int* in_sizes, int n_in,
                              void* d_out, int out_size, void* d_ws, size_t ws_size,
                              hipStream_t stream) {
  const float* x  = (const float*)d_in[0];
  const float* Wq = (const float*)d_in[1];
  const float* Wk = (const float*)d_in[2];
  const float* Wv = (const float*)d_in[3];
  float* out = (float*)d_out;
  char* ws = (char*)d_ws;
  // ws layout: Wt 384KB | Q 2MB | Kf 2MB | Vf 2MB  (6.375 MB, proven size)
  u16* Wt = (u16*)(ws);
  u16* Q  = (u16*)(ws + 0x60000);
  u16* Kf = (u16*)(ws + 0x260000);
  u16* Vf = (u16*)(ws + 0x460000);

  hipLaunchKernelGGL(wtrans_kernel, dim3(48), dim3(256), 0, stream, Wq, Wk, Wv, Wt);
  hipLaunchKernelGGL(proj_kernel, dim3(512), dim3(256), 0, stream, x, Wt, Q, Kf, Vf);
  hipLaunchKernelGGL(attn_kernel, dim3(512), dim3(256), 0, stream, Q, Kf, Vf, out);
}